// Round 9
// baseline (265.068 us; speedup 1.0000x reference)
//
#include <hip/hip_runtime.h>
#include <hip/hip_bf16.h>

// SupplyChainGNN: 3-layer GCN, N=50000, E=800000, H=64.
// Round 20: R19 gather/conv untouched (branch-free padded gather = best, 208.6).
// CSR build rewritten: 4-pass bucket sort (hist/scan/bin/csr, ~20us, 2 E-sized
// ebuf round trips) -> global-atomic 3.5-pass build (~11us): zero_deg, deg_pass
// (L2-resident scattered atomics on deg[N]), scan_nodes (per-bucket scan, padded
// BCAP layout + pad fills + cur init), scatter_pass (atomic cur -> csr_pad).
// ebuf eliminated.

#define HDIM 64
#define NPB 256         // nodes per bucket (scan granularity)
#define NPB_SHIFT 8
#define BCAP 8192       // padded edge capacity per bucket (mean ~5050, 50-sigma safe)

__device__ inline unsigned bfpack(float lo, float hi) {
    unsigned ul = __float_as_uint(lo), uh = __float_as_uint(hi);
    ul += 0x7fffu + ((ul >> 16) & 1u);
    uh += 0x7fffu + ((uh >> 16) & 1u);
    return (ul >> 16) | (uh & 0xffff0000u);
}

__device__ inline float2 bfunpack(unsigned u) {
    float2 r;
    r.x = __uint_as_float(u << 16);
    r.y = __uint_as_float(u & 0xffff0000u);
    return r;
}

// CSR build pass 0: zero the degree counters.
__global__ __launch_bounds__(256) void zero_deg(unsigned* __restrict__ deg, int N) {
    int i = blockIdx.x * 256 + threadIdx.x;
    if (i < N) deg[i] = 0u;
}

// CSR build pass 1: deg[d] counts via device atomics (deg = 200KB, L2-resident).
__global__ __launch_bounds__(256) void deg_pass(const int* __restrict__ dst,
                                                unsigned* __restrict__ deg, int E) {
    int stride = gridDim.x * 256;
    for (int e = blockIdx.x * 256 + threadIdx.x; e < E; e += stride)
        atomicAdd(&deg[dst[e]], 1u);
}

// CSR build pass 2: per-bucket exclusive scan of padded counts -> row_ptr
// (bucket-region layout k*BCAP + offset), pc8, dinv, cur init, pad fills.
__global__ __launch_bounds__(256) void scan_nodes(const unsigned* __restrict__ deg,
                                                  unsigned* __restrict__ row_ptr,
                                                  unsigned short* __restrict__ pc8,
                                                  float* __restrict__ dinv,
                                                  unsigned* __restrict__ cur,
                                                  int* __restrict__ csr_pad,
                                                  int N) {
    __shared__ unsigned sc[NPB];
    int t = threadIdx.x, k = blockIdx.x;
    int node = (k << NPB_SHIFT) + t;
    unsigned v = (node < N) ? deg[node] : 0u;
    unsigned pcnt = (v + 7u) & ~7u;   // padded to multiple of 8 (0 stays 0)
    sc[t] = pcnt;
    __syncthreads();
#pragma unroll
    for (int off = 1; off < NPB; off <<= 1) {
        unsigned u = (t >= off) ? sc[t - off] : 0u;
        __syncthreads();
        sc[t] += u;
        __syncthreads();
    }
    unsigned pos0 = (unsigned)k * BCAP + (sc[t] - pcnt);
    if (node < N) {
        row_ptr[node] = pos0;
        pc8[node] = (unsigned short)(pcnt >> 3);
        dinv[node] = rsqrtf((float)(v + 1u));
        cur[node] = pos0;
        for (unsigned j = v; j < pcnt; j++) csr_pad[pos0 + j] = N;  // pad -> zero row
    }
}

// CSR build pass 3: scatter src to final padded position via atomic cur.
__global__ __launch_bounds__(256) void scatter_pass(const int* __restrict__ ei,
                                                    unsigned* __restrict__ cur,
                                                    int* __restrict__ csr_pad,
                                                    int E) {
    int stride = gridDim.x * 256;
    for (int e = blockIdx.x * 256 + threadIdx.x; e < E; e += stride) {
        int s = ei[e];
        int d = ei[E + e];
        unsigned pos = atomicAdd(&cur[d], 1u);
        csr_pad[pos] = s;
    }
}

// hn[i] = bf16( dinv[i] * relu(x@W+b) ); thread per feature-pair.
// Row N (dummy) of BOTH ping-pong buffers is zeroed here.
__global__ __launch_bounds__(256) void encoder(const float* __restrict__ x,
                                               const float* __restrict__ W,
                                               const float* __restrict__ b,
                                               const float* __restrict__ dinv,
                                               unsigned* __restrict__ hnA,
                                               unsigned* __restrict__ hnB, int N) {
    int t = blockIdx.x * 256 + threadIdx.x;
    int i = t >> 5, jp = t & 31;
    if (i > N) return;
    if (i == N) {          // dummy zero row for padded gather
        hnA[t] = 0u;
        hnB[t] = 0u;
        return;
    }
    int j0 = 2 * jp;
    float a0 = b[j0], a1 = b[j0 + 1];
#pragma unroll
    for (int k = 0; k < 5; k++) {
        float xv = x[i * 5 + k];
        a0 = fmaf(xv, W[k * 64 + j0], a0);
        a1 = fmaf(xv, W[k * 64 + j0 + 1], a1);
    }
    float di = dinv[i];
    hnA[t] = bfpack(di * fmaxf(a0, 0.0f), di * fmaxf(a1, 0.0f));
}

#define ACC4(A, V) do {                                                         \
    float2 _p = bfunpack((V).x), _q = bfunpack((V).y);                          \
    (A).x += _p.x; (A).y += _p.y; (A).z += _q.x; (A).w += _q.y;                 \
} while (0)

// Branch-free quarter-wave gather: nb batches of 8 (list padded with src=N
// -> zero row, L1-resident). Lane fl owns features 4fl..4fl+3 (uint2 = 8B,
// one 128B line per edge). 8 loads in flight; no remainder, no masks.
__device__ inline float4 gather_pad_q(const int* __restrict__ idx, int nb,
                                      const uint2* __restrict__ hp, int fl,
                                      float4 a0) {
    float4 a1 = {0.f, 0.f, 0.f, 0.f}, a2 = a1, a3 = a1;
    if (nb > 0) {
        int s0 = idx[0], s1 = idx[1], s2 = idx[2], s3 = idx[3];
        int s4 = idx[4], s5 = idx[5], s6 = idx[6], s7 = idx[7];
        int u = 0;
        while (true) {
            uint2 v0 = hp[(size_t)s0 * 16 + fl];
            uint2 v1 = hp[(size_t)s1 * 16 + fl];
            uint2 v2 = hp[(size_t)s2 * 16 + fl];
            uint2 v3 = hp[(size_t)s3 * 16 + fl];
            uint2 v4 = hp[(size_t)s4 * 16 + fl];
            uint2 v5 = hp[(size_t)s5 * 16 + fl];
            uint2 v6 = hp[(size_t)s6 * 16 + fl];
            uint2 v7 = hp[(size_t)s7 * 16 + fl];
            u += 8;
            bool more = (u >> 3) < nb;
            if (more) {
                s0 = idx[u + 0]; s1 = idx[u + 1]; s2 = idx[u + 2]; s3 = idx[u + 3];
                s4 = idx[u + 4]; s5 = idx[u + 5]; s6 = idx[u + 6]; s7 = idx[u + 7];
            }
            ACC4(a0, v0); ACC4(a1, v1); ACC4(a2, v2); ACC4(a3, v3);
            ACC4(a0, v4); ACC4(a1, v5); ACC4(a2, v6); ACC4(a3, v7);
            if (!more) break;
        }
    }
    a0.x += a1.x; a0.y += a1.y; a0.z += a1.z; a0.w += a1.w;
    a2.x += a3.x; a2.y += a3.y; a2.z += a3.z; a2.w += a3.w;
    a0.x += a2.x; a0.y += a2.y; a0.z += a2.z; a0.w += a2.w;
    return a0;
}

// 8 FMAs: acc0,acc1 (float4) += hk * 8-wide W row segment (wave-uniform)
#define CONV_K8(WROW, HK) do {                                                  \
    float4 wa = ((const float4*)(WROW))[0];                                     \
    float4 wb = ((const float4*)(WROW))[1];                                     \
    acc0.x = fmaf(HK, wa.x, acc0.x); acc0.y = fmaf(HK, wa.y, acc0.y);           \
    acc0.z = fmaf(HK, wa.z, acc0.z); acc0.w = fmaf(HK, wa.w, acc0.w);           \
    acc1.x = fmaf(HK, wb.x, acc1.x); acc1.y = fmaf(HK, wb.y, acc1.y);           \
    acc1.z = fmaf(HK, wb.z, acc1.z); acc1.w = fmaf(HK, wb.w, acc1.w);           \
} while (0)

// Fused gather+conv, 64 nodes/block, 512 threads (32 quarter-waves x 2 nodes).
// Conv: thread per (node n=tid&63, 8 outputs jb=(tid>>6)*8); W rows via
// wave-uniform scalar loads.
__global__ __launch_bounds__(512, 4) void gconv(const unsigned* __restrict__ row_ptr,
                                                const unsigned short* __restrict__ pc8,
                                                const int* __restrict__ csr_pad,
                                                const unsigned* __restrict__ hn_in,
                                                const float* __restrict__ W,
                                                const float* __restrict__ b,
                                                const float* __restrict__ dinv,
                                                unsigned* __restrict__ hn_out, int N) {
    __shared__ float ybuf[64 * 65];   // [feature][node]
    int tid = threadIdx.x;
    int qw = tid >> 4, fl = tid & 15;
    int base = blockIdx.x * 64;
    const uint2* hp = (const uint2*)hn_in;
    for (int s = 0; s < 2; s++) {
        int n = qw * 2 + s;
        int i = base + n;
        if (i < N) {
            uint2 sv = hp[(size_t)i * 16 + fl];   // self term
            float4 a;
            float2 p = bfunpack(sv.x), q = bfunpack(sv.y);
            a.x = p.x; a.y = p.y; a.z = q.x; a.w = q.y;
            a = gather_pad_q(csr_pad + row_ptr[i], (int)pc8[i], hp, fl, a);
            ybuf[(4 * fl + 0) * 65 + n] = a.x;
            ybuf[(4 * fl + 1) * 65 + n] = a.y;
            ybuf[(4 * fl + 2) * 65 + n] = a.z;
            ybuf[(4 * fl + 3) * 65 + n] = a.w;
        }
    }
    __syncthreads();
    int n = tid & 63;
    int qt = __builtin_amdgcn_readfirstlane(tid >> 6);   // 0..7, wave-uniform
    int i = base + n;
    if (i >= N) return;
    int jb = qt * 8;
    float di = dinv[i];
    float4 acc0 = {0.f, 0.f, 0.f, 0.f}, acc1 = acc0;
    const float* Wj = W + jb;
#pragma unroll
    for (int k = 0; k < 64; k++) {
        float hk = ybuf[k * 65 + n];
        CONV_K8(Wj + k * 64, hk);
    }
    const float* bj = b + jb;
    float4 y0, y1;
    y0.x = fmaxf(fmaf(di, acc0.x, bj[0]), 0.f) * di;
    y0.y = fmaxf(fmaf(di, acc0.y, bj[1]), 0.f) * di;
    y0.z = fmaxf(fmaf(di, acc0.z, bj[2]), 0.f) * di;
    y0.w = fmaxf(fmaf(di, acc0.w, bj[3]), 0.f) * di;
    y1.x = fmaxf(fmaf(di, acc1.x, bj[4]), 0.f) * di;
    y1.y = fmaxf(fmaf(di, acc1.y, bj[5]), 0.f) * di;
    y1.z = fmaxf(fmaf(di, acc1.z, bj[6]), 0.f) * di;
    y1.w = fmaxf(fmaf(di, acc1.w, bj[7]), 0.f) * di;
    uint4 p;
    p.x = bfpack(y0.x, y0.y);
    p.y = bfpack(y0.z, y0.w);
    p.z = bfpack(y1.x, y1.y);
    p.w = bfpack(y1.z, y1.w);
    *(uint4*)(hn_out + (size_t)i * 32 + qt * 4) = p;
}

// Layer 2: fused gather + conv + both MLP heads -> out (512 threads).
__global__ __launch_bounds__(512, 4) void gconv_heads(const unsigned* __restrict__ row_ptr,
                                                      const unsigned short* __restrict__ pc8,
                                                      const int* __restrict__ csr_pad,
                                                      const unsigned* __restrict__ hn_in,
                                                      const float* __restrict__ W,
                                                      const float* __restrict__ b,
                                                      const float* __restrict__ dinv,
                                                      const float* __restrict__ W_d1, const float* __restrict__ b_d1,
                                                      const float* __restrict__ W_d2, const float* __restrict__ b_d2,
                                                      const float* __restrict__ W_i1, const float* __restrict__ b_i1,
                                                      const float* __restrict__ W_i2, const float* __restrict__ b_i2,
                                                      float* __restrict__ out, int N) {
    __shared__ float ybuf[64 * 65];   // gathered rows, later y rows (feature-major)
    __shared__ float opart[512];
    int tid = threadIdx.x;
    int qw = tid >> 4, fl = tid & 15;
    int base = blockIdx.x * 64;
    const uint2* hp = (const uint2*)hn_in;
    for (int s = 0; s < 2; s++) {
        int n = qw * 2 + s;
        int i = base + n;
        if (i < N) {
            uint2 sv = hp[(size_t)i * 16 + fl];   // self term
            float4 a;
            float2 p = bfunpack(sv.x), q = bfunpack(sv.y);
            a.x = p.x; a.y = p.y; a.z = q.x; a.w = q.y;
            a = gather_pad_q(csr_pad + row_ptr[i], (int)pc8[i], hp, fl, a);
            ybuf[(4 * fl + 0) * 65 + n] = a.x;
            ybuf[(4 * fl + 1) * 65 + n] = a.y;
            ybuf[(4 * fl + 2) * 65 + n] = a.z;
            ybuf[(4 * fl + 3) * 65 + n] = a.w;
        }
    }
    __syncthreads();
    int n = tid & 63;
    int qt = __builtin_amdgcn_readfirstlane(tid >> 6);   // 0..7, wave-uniform
    int i = base + n;
    int jb = qt * 8;
    float y[8];
    if (i < N) {
        float di = dinv[i];
        float4 acc0 = {0.f, 0.f, 0.f, 0.f}, acc1 = acc0;
        const float* Wj = W + jb;
#pragma unroll
        for (int k = 0; k < 64; k++) {
            float hk = ybuf[k * 65 + n];
            CONV_K8(Wj + k * 64, hk);
        }
        const float* bj = b + jb;
        y[0] = fmaxf(fmaf(di, acc0.x, bj[0]), 0.f);
        y[1] = fmaxf(fmaf(di, acc0.y, bj[1]), 0.f);
        y[2] = fmaxf(fmaf(di, acc0.z, bj[2]), 0.f);
        y[3] = fmaxf(fmaf(di, acc0.w, bj[3]), 0.f);
        y[4] = fmaxf(fmaf(di, acc1.x, bj[4]), 0.f);
        y[5] = fmaxf(fmaf(di, acc1.y, bj[5]), 0.f);
        y[6] = fmaxf(fmaf(di, acc1.z, bj[6]), 0.f);
        y[7] = fmaxf(fmaf(di, acc1.w, bj[7]), 0.f);
    }
    __syncthreads();   // all conv reads of ybuf done
    if (i < N) {
#pragma unroll
        for (int jj = 0; jj < 8; jj++) ybuf[(jb + jj) * 65 + n] = y[jj];
    }
    __syncthreads();
    // heads: hd = tid>>8 (head), q2 = (tid>>6)&3 (8-out group), n = tid&63
    int hd = __builtin_amdgcn_readfirstlane(tid >> 8);        // 0/1, wave-uniform
    int q2 = __builtin_amdgcn_readfirstlane((tid >> 6) & 3);  // 0..3, wave-uniform
    int hb = q2 * 8;
    float op = 0.f;
    if (i < N) {
        const float* W1 = (hd ? W_i1 : W_d1) + hb;   // [64][32] row-major
        const float* b1 = (hd ? b_i1 : b_d1) + hb;
        const float* W2 = (hd ? W_i2 : W_d2) + hb;
        float4 acc0 = {0.f, 0.f, 0.f, 0.f}, acc1 = acc0;
#pragma unroll
        for (int k = 0; k < 64; k++) {
            float hk = ybuf[k * 65 + n];
            CONV_K8(W1 + k * 32, hk);
        }
        op = fmaf(fmaxf(acc0.x + b1[0], 0.f), W2[0], op);
        op = fmaf(fmaxf(acc0.y + b1[1], 0.f), W2[1], op);
        op = fmaf(fmaxf(acc0.z + b1[2], 0.f), W2[2], op);
        op = fmaf(fmaxf(acc0.w + b1[3], 0.f), W2[3], op);
        op = fmaf(fmaxf(acc1.x + b1[4], 0.f), W2[4], op);
        op = fmaf(fmaxf(acc1.y + b1[5], 0.f), W2[5], op);
        op = fmaf(fmaxf(acc1.z + b1[6], 0.f), W2[6], op);
        op = fmaf(fmaxf(acc1.w + b1[7], 0.f), W2[7], op);
    }
    opart[tid] = op;
    __syncthreads();
    if (tid < 128) {
        int n2 = tid & 63, h2 = tid >> 6;
        int i2 = base + n2;
        if (i2 < N) {
            int o0 = h2 * 256 + n2;
            float o = opart[o0] + opart[o0 + 64] + opart[o0 + 128] + opart[o0 + 192]
                    + (h2 ? b_i2[0] : b_d2[0]);
            out[(size_t)h2 * N + i2] = o;
        }
    }
}

extern "C" void kernel_launch(void* const* d_in, const int* in_sizes, int n_in,
                              void* d_out, int out_size, void* d_ws, size_t ws_size,
                              hipStream_t stream) {
    const float* x      = (const float*)d_in[0];
    const int*   ei     = (const int*)d_in[1];
    const float* W_enc  = (const float*)d_in[2];
    const float* b_enc  = (const float*)d_in[3];
    const float* conv_W = (const float*)d_in[4];
    const float* conv_b = (const float*)d_in[5];
    const float* W_d1   = (const float*)d_in[6];
    const float* b_d1   = (const float*)d_in[7];
    const float* W_d2   = (const float*)d_in[8];
    const float* b_d2   = (const float*)d_in[9];
    const float* W_i1   = (const float*)d_in[10];
    const float* b_i1   = (const float*)d_in[11];
    const float* W_i2   = (const float*)d_in[12];
    const float* b_i2   = (const float*)d_in[13];

    const int N = in_sizes[0] / 5;
    const int E = in_sizes[1] / 2;
    const int NB = (N + NPB - 1) >> NPB_SHIFT;   // <= 256

    // Workspace: hnA/hnB have N+1 rows (row N = dummy zeros for padding).
    unsigned* hnA = (unsigned*)d_ws;                      // (N+1)*32 bf16x2
    unsigned* hnB = hnA + (size_t)(N + 1) * 32;           // (N+1)*32
    float* dinv = (float*)(hnB + (size_t)(N + 1) * 32);
    unsigned* row_ptr = (unsigned*)(dinv + N);            // [N]
    unsigned short* pc8 = (unsigned short*)(row_ptr + N); // [N] (N even -> 4B-aligned end)
    unsigned* deg = (unsigned*)(pc8 + N);                 // [N]
    unsigned* cur = deg + N;                              // [N]
    int* csr_pad  = (int*)(cur + N);                      // [NB*BCAP]
    float* out = (float*)d_out;

    const int gBlocks = (N + 63) / 64;   // 64 nodes per fused block

    // CSR build: global-atomic 3.5-pass (deg counters are L2-resident)
    zero_deg<<<(N + 255) / 256, 256, 0, stream>>>(deg, N);
    deg_pass<<<2048, 256, 0, stream>>>(ei + E, deg, E);
    scan_nodes<<<NB, 256, 0, stream>>>(deg, row_ptr, pc8, dinv, cur, csr_pad, N);
    scatter_pass<<<2048, 256, 0, stream>>>(ei, cur, csr_pad, E);

    // encoder -> hnA (bf16, dinv-prescaled); zeroes dummy row N of hnA+hnB
    encoder<<<((N + 1) * 32 + 255) / 256, 256, 0, stream>>>(x, W_enc, b_enc, dinv,
                                                            hnA, hnB, N);

    // fused gather+conv per layer (ping-pong hnA/hnB), layer 2 fused with heads
    gconv<<<gBlocks, 512, 0, stream>>>(row_ptr, pc8, csr_pad, hnA,
                                       conv_W + 0 * HDIM * HDIM, conv_b + 0 * HDIM,
                                       dinv, hnB, N);
    gconv<<<gBlocks, 512, 0, stream>>>(row_ptr, pc8, csr_pad, hnB,
                                       conv_W + 1 * HDIM * HDIM, conv_b + 1 * HDIM,
                                       dinv, hnA, N);
    gconv_heads<<<gBlocks, 512, 0, stream>>>(row_ptr, pc8, csr_pad, hnA,
                                             conv_W + 2 * HDIM * HDIM, conv_b + 2 * HDIM,
                                             dinv, W_d1, b_d1, W_d2, b_d2,
                                             W_i1, b_i1, W_i2, b_i2, out, N);
}

// Round 10
// 205.913 us; speedup vs baseline: 1.2873x; 1.2873x over previous
//
#include <hip/hip_runtime.h>
#include <hip/hip_bf16.h>

// SupplyChainGNN: 3-layer GCN, N=50000, E=800000, H=64.
// Round 21: REVERT to R19 (best measured: 208.6us). R20's global-atomic CSR
// build regressed hard (scatter_pass 57us: random 4B writes dirty full L2
// lines -> 51MB write traffic + scattered atomic RMW). The R19 bucket sort
// keeps all E-sized passes coalesced. Gather/conv unchanged: branch-free
// padded quarter-wave gather (one 128B line/edge, no remainder), wave-uniform
// scalar-load conv, fused heads.

#define HDIM 64
#define PB 256          // blocks in hist/bin passes
#define NPB 256         // nodes per bucket
#define NPB_SHIFT 8
#define BCAP 8192       // padded edge capacity per bucket (mean 4096+pad<=1792)

__device__ inline unsigned bfpack(float lo, float hi) {
    unsigned ul = __float_as_uint(lo), uh = __float_as_uint(hi);
    ul += 0x7fffu + ((ul >> 16) & 1u);
    uh += 0x7fffu + ((uh >> 16) & 1u);
    return (ul >> 16) | (uh & 0xffff0000u);
}

__device__ inline float2 bfunpack(unsigned u) {
    float2 r;
    r.x = __uint_as_float(u << 16);
    r.y = __uint_as_float(u & 0xffff0000u);
    return r;
}

// Pass 1: histT[k*PB + p] = #edges of block p with dst in bucket k  (NB<=256)
__global__ __launch_bounds__(256) void hist_pass(const int* __restrict__ dst,
                                                 unsigned* __restrict__ histT,
                                                 int E, int NB) {
    __shared__ unsigned h[256];
    int t = threadIdx.x, p = blockIdx.x;
    h[t] = 0u;
    __syncthreads();
    int chunk = (E + PB - 1) / PB;
    int lo = p * chunk, hi = min(lo + chunk, E);
    for (int e = lo + t; e < hi; e += 256)
        atomicAdd(&h[dst[e] >> NPB_SHIFT], 1u);
    __syncthreads();
    if (t < NB) histT[t * PB + p] = h[t];
}

// Pass 2: per-bucket exclusive scan of its PB per-block counts (in place);
// bucket total -> btot[k].
__global__ __launch_bounds__(PB) void scan_bucket(unsigned* __restrict__ histT,
                                                  unsigned* __restrict__ btot) {
    __shared__ unsigned s[PB];
    int t = threadIdx.x, k = blockIdx.x;
    unsigned v = histT[k * PB + t];
    s[t] = v;
    __syncthreads();
#pragma unroll
    for (int off = 1; off < PB; off <<= 1) {
        unsigned u = (t >= off) ? s[t - off] : 0u;
        __syncthreads();
        s[t] += u;
        __syncthreads();
    }
    histT[k * PB + t] = s[t] - v;
    if (t == PB - 1) btot[k] = s[t];
}

// Pass 3: scatter packed (dst_local<<16)|src into bucket-grouped ebuf.
__global__ __launch_bounds__(256) void bin_pass(const int* __restrict__ ei,
                                                const unsigned* __restrict__ histT,
                                                const unsigned* __restrict__ btot,
                                                unsigned* __restrict__ ebuf,
                                                int E, int NB) {
    __shared__ unsigned bb[256];
    __shared__ unsigned cur[256];
    int t = threadIdx.x, p = blockIdx.x;
    unsigned bv = (t < NB) ? btot[t] : 0u;
    bb[t] = bv;
    __syncthreads();
#pragma unroll
    for (int off = 1; off < 256; off <<= 1) {
        unsigned u = (t >= off) ? bb[t - off] : 0u;
        __syncthreads();
        bb[t] += u;
        __syncthreads();
    }
    if (t < NB) cur[t] = histT[t * PB + p] + (bb[t] - bv);
    __syncthreads();
    int chunk = (E + PB - 1) / PB;
    int lo = p * chunk, hi = min(lo + chunk, E);
    for (int e = lo + t; e < hi; e += 256) {
        unsigned sN = (unsigned)ei[e];
        unsigned dN = (unsigned)ei[E + e];
        unsigned pos = atomicAdd(&cur[dN >> NPB_SHIFT], 1u);
        ebuf[pos] = ((dN & (NPB - 1u)) << 16) | sN;
    }
}

// Pass 4: one block per bucket -> padded CSR region [k*BCAP, ...), row_ptr,
// pc8 (batches of 8), dinv. Pad slots get dummy src = N (zero row).
__global__ __launch_bounds__(256) void csr_pass(const unsigned* __restrict__ ebuf,
                                                const unsigned* __restrict__ btot,
                                                unsigned* __restrict__ row_ptr,
                                                unsigned short* __restrict__ pc8,
                                                float* __restrict__ dinv,
                                                int* __restrict__ csr_pad,
                                                int N, int E, int NB) {
    __shared__ unsigned bb[256];
    __shared__ unsigned cntL[NPB];
    __shared__ unsigned sc[NPB];
    __shared__ unsigned cur[NPB];
    int t = threadIdx.x, k = blockIdx.x;
    unsigned bv = (t < NB) ? btot[t] : 0u;
    bb[t] = bv;
    __syncthreads();
#pragma unroll
    for (int off = 1; off < 256; off <<= 1) {
        unsigned u = (t >= off) ? bb[t - off] : 0u;
        __syncthreads();
        bb[t] += u;
        __syncthreads();
    }
    unsigned e1 = bb[k];
    unsigned e0 = e1 - btot[k];
    int nbase = k << NPB_SHIFT;
    cntL[t] = 0u;
    __syncthreads();
    for (unsigned e = e0 + t; e < e1; e += 256)
        atomicAdd(&cntL[ebuf[e] >> 16], 1u);
    __syncthreads();
    unsigned v = cntL[t];
    unsigned pcnt = (v + 7u) & ~7u;   // padded to multiple of 8 (0 stays 0)
    sc[t] = pcnt;
    __syncthreads();
#pragma unroll
    for (int off = 1; off < NPB; off <<= 1) {
        unsigned u = (t >= off) ? sc[t - off] : 0u;
        __syncthreads();
        sc[t] += u;
        __syncthreads();
    }
    unsigned pos0 = (unsigned)k * BCAP + (sc[t] - pcnt);
    cur[t] = pos0;
    int node = nbase + t;
    if (node < N) {
        row_ptr[node] = pos0;
        pc8[node] = (unsigned short)(pcnt >> 3);
        dinv[node] = rsqrtf((float)(v + 1u));
        for (unsigned j = v; j < pcnt; j++) csr_pad[pos0 + j] = N;  // pad -> zero row
    }
    __syncthreads();
    for (unsigned e = e0 + t; e < e1; e += 256) {
        unsigned ed = ebuf[e];
        unsigned pos = atomicAdd(&cur[ed >> 16], 1u);
        csr_pad[pos] = (int)(ed & 0xffffu);
    }
}

// hn[i] = bf16( dinv[i] * relu(x@W+b) ); thread per feature-pair.
// Row N (dummy) of BOTH ping-pong buffers is zeroed here.
__global__ __launch_bounds__(256) void encoder(const float* __restrict__ x,
                                               const float* __restrict__ W,
                                               const float* __restrict__ b,
                                               const float* __restrict__ dinv,
                                               unsigned* __restrict__ hnA,
                                               unsigned* __restrict__ hnB, int N) {
    int t = blockIdx.x * 256 + threadIdx.x;
    int i = t >> 5, jp = t & 31;
    if (i > N) return;
    if (i == N) {          // dummy zero row for padded gather
        hnA[t] = 0u;
        hnB[t] = 0u;
        return;
    }
    int j0 = 2 * jp;
    float a0 = b[j0], a1 = b[j0 + 1];
#pragma unroll
    for (int k = 0; k < 5; k++) {
        float xv = x[i * 5 + k];
        a0 = fmaf(xv, W[k * 64 + j0], a0);
        a1 = fmaf(xv, W[k * 64 + j0 + 1], a1);
    }
    float di = dinv[i];
    hnA[t] = bfpack(di * fmaxf(a0, 0.0f), di * fmaxf(a1, 0.0f));
}

#define ACC4(A, V) do {                                                         \
    float2 _p = bfunpack((V).x), _q = bfunpack((V).y);                          \
    (A).x += _p.x; (A).y += _p.y; (A).z += _q.x; (A).w += _q.y;                 \
} while (0)

// Branch-free quarter-wave gather: nb batches of 8 (list padded with src=N
// -> zero row, L1-resident). Lane fl owns features 4fl..4fl+3 (uint2 = 8B,
// one 128B line per edge). 8 loads in flight; no remainder, no masks.
__device__ inline float4 gather_pad_q(const int* __restrict__ idx, int nb,
                                      const uint2* __restrict__ hp, int fl,
                                      float4 a0) {
    float4 a1 = {0.f, 0.f, 0.f, 0.f}, a2 = a1, a3 = a1;
    if (nb > 0) {
        int s0 = idx[0], s1 = idx[1], s2 = idx[2], s3 = idx[3];
        int s4 = idx[4], s5 = idx[5], s6 = idx[6], s7 = idx[7];
        int u = 0;
        while (true) {
            uint2 v0 = hp[(size_t)s0 * 16 + fl];
            uint2 v1 = hp[(size_t)s1 * 16 + fl];
            uint2 v2 = hp[(size_t)s2 * 16 + fl];
            uint2 v3 = hp[(size_t)s3 * 16 + fl];
            uint2 v4 = hp[(size_t)s4 * 16 + fl];
            uint2 v5 = hp[(size_t)s5 * 16 + fl];
            uint2 v6 = hp[(size_t)s6 * 16 + fl];
            uint2 v7 = hp[(size_t)s7 * 16 + fl];
            u += 8;
            bool more = (u >> 3) < nb;
            if (more) {
                s0 = idx[u + 0]; s1 = idx[u + 1]; s2 = idx[u + 2]; s3 = idx[u + 3];
                s4 = idx[u + 4]; s5 = idx[u + 5]; s6 = idx[u + 6]; s7 = idx[u + 7];
            }
            ACC4(a0, v0); ACC4(a1, v1); ACC4(a2, v2); ACC4(a3, v3);
            ACC4(a0, v4); ACC4(a1, v5); ACC4(a2, v6); ACC4(a3, v7);
            if (!more) break;
        }
    }
    a0.x += a1.x; a0.y += a1.y; a0.z += a1.z; a0.w += a1.w;
    a2.x += a3.x; a2.y += a3.y; a2.z += a3.z; a2.w += a3.w;
    a0.x += a2.x; a0.y += a2.y; a0.z += a2.z; a0.w += a2.w;
    return a0;
}

// 8 FMAs: acc0,acc1 (float4) += hk * 8-wide W row segment (wave-uniform)
#define CONV_K8(WROW, HK) do {                                                  \
    float4 wa = ((const float4*)(WROW))[0];                                     \
    float4 wb = ((const float4*)(WROW))[1];                                     \
    acc0.x = fmaf(HK, wa.x, acc0.x); acc0.y = fmaf(HK, wa.y, acc0.y);           \
    acc0.z = fmaf(HK, wa.z, acc0.z); acc0.w = fmaf(HK, wa.w, acc0.w);           \
    acc1.x = fmaf(HK, wb.x, acc1.x); acc1.y = fmaf(HK, wb.y, acc1.y);           \
    acc1.z = fmaf(HK, wb.z, acc1.z); acc1.w = fmaf(HK, wb.w, acc1.w);           \
} while (0)

// Fused gather+conv, 64 nodes/block, 512 threads (32 quarter-waves x 2 nodes).
// Conv: thread per (node n=tid&63, 8 outputs jb=(tid>>6)*8); W rows via
// wave-uniform scalar loads.
__global__ __launch_bounds__(512, 4) void gconv(const unsigned* __restrict__ row_ptr,
                                                const unsigned short* __restrict__ pc8,
                                                const int* __restrict__ csr_pad,
                                                const unsigned* __restrict__ hn_in,
                                                const float* __restrict__ W,
                                                const float* __restrict__ b,
                                                const float* __restrict__ dinv,
                                                unsigned* __restrict__ hn_out, int N) {
    __shared__ float ybuf[64 * 65];   // [feature][node]
    int tid = threadIdx.x;
    int qw = tid >> 4, fl = tid & 15;
    int base = blockIdx.x * 64;
    const uint2* hp = (const uint2*)hn_in;
    for (int s = 0; s < 2; s++) {
        int n = qw * 2 + s;
        int i = base + n;
        if (i < N) {
            uint2 sv = hp[(size_t)i * 16 + fl];   // self term
            float4 a;
            float2 p = bfunpack(sv.x), q = bfunpack(sv.y);
            a.x = p.x; a.y = p.y; a.z = q.x; a.w = q.y;
            a = gather_pad_q(csr_pad + row_ptr[i], (int)pc8[i], hp, fl, a);
            ybuf[(4 * fl + 0) * 65 + n] = a.x;
            ybuf[(4 * fl + 1) * 65 + n] = a.y;
            ybuf[(4 * fl + 2) * 65 + n] = a.z;
            ybuf[(4 * fl + 3) * 65 + n] = a.w;
        }
    }
    __syncthreads();
    int n = tid & 63;
    int qt = __builtin_amdgcn_readfirstlane(tid >> 6);   // 0..7, wave-uniform
    int i = base + n;
    if (i >= N) return;
    int jb = qt * 8;
    float di = dinv[i];
    float4 acc0 = {0.f, 0.f, 0.f, 0.f}, acc1 = acc0;
    const float* Wj = W + jb;
#pragma unroll
    for (int k = 0; k < 64; k++) {
        float hk = ybuf[k * 65 + n];
        CONV_K8(Wj + k * 64, hk);
    }
    const float* bj = b + jb;
    float4 y0, y1;
    y0.x = fmaxf(fmaf(di, acc0.x, bj[0]), 0.f) * di;
    y0.y = fmaxf(fmaf(di, acc0.y, bj[1]), 0.f) * di;
    y0.z = fmaxf(fmaf(di, acc0.z, bj[2]), 0.f) * di;
    y0.w = fmaxf(fmaf(di, acc0.w, bj[3]), 0.f) * di;
    y1.x = fmaxf(fmaf(di, acc1.x, bj[4]), 0.f) * di;
    y1.y = fmaxf(fmaf(di, acc1.y, bj[5]), 0.f) * di;
    y1.z = fmaxf(fmaf(di, acc1.z, bj[6]), 0.f) * di;
    y1.w = fmaxf(fmaf(di, acc1.w, bj[7]), 0.f) * di;
    uint4 p;
    p.x = bfpack(y0.x, y0.y);
    p.y = bfpack(y0.z, y0.w);
    p.z = bfpack(y1.x, y1.y);
    p.w = bfpack(y1.z, y1.w);
    *(uint4*)(hn_out + (size_t)i * 32 + qt * 4) = p;
}

// Layer 2: fused gather + conv + both MLP heads -> out (512 threads).
__global__ __launch_bounds__(512, 4) void gconv_heads(const unsigned* __restrict__ row_ptr,
                                                      const unsigned short* __restrict__ pc8,
                                                      const int* __restrict__ csr_pad,
                                                      const unsigned* __restrict__ hn_in,
                                                      const float* __restrict__ W,
                                                      const float* __restrict__ b,
                                                      const float* __restrict__ dinv,
                                                      const float* __restrict__ W_d1, const float* __restrict__ b_d1,
                                                      const float* __restrict__ W_d2, const float* __restrict__ b_d2,
                                                      const float* __restrict__ W_i1, const float* __restrict__ b_i1,
                                                      const float* __restrict__ W_i2, const float* __restrict__ b_i2,
                                                      float* __restrict__ out, int N) {
    __shared__ float ybuf[64 * 65];   // gathered rows, later y rows (feature-major)
    __shared__ float opart[512];
    int tid = threadIdx.x;
    int qw = tid >> 4, fl = tid & 15;
    int base = blockIdx.x * 64;
    const uint2* hp = (const uint2*)hn_in;
    for (int s = 0; s < 2; s++) {
        int n = qw * 2 + s;
        int i = base + n;
        if (i < N) {
            uint2 sv = hp[(size_t)i * 16 + fl];   // self term
            float4 a;
            float2 p = bfunpack(sv.x), q = bfunpack(sv.y);
            a.x = p.x; a.y = p.y; a.z = q.x; a.w = q.y;
            a = gather_pad_q(csr_pad + row_ptr[i], (int)pc8[i], hp, fl, a);
            ybuf[(4 * fl + 0) * 65 + n] = a.x;
            ybuf[(4 * fl + 1) * 65 + n] = a.y;
            ybuf[(4 * fl + 2) * 65 + n] = a.z;
            ybuf[(4 * fl + 3) * 65 + n] = a.w;
        }
    }
    __syncthreads();
    int n = tid & 63;
    int qt = __builtin_amdgcn_readfirstlane(tid >> 6);   // 0..7, wave-uniform
    int i = base + n;
    int jb = qt * 8;
    float y[8];
    if (i < N) {
        float di = dinv[i];
        float4 acc0 = {0.f, 0.f, 0.f, 0.f}, acc1 = acc0;
        const float* Wj = W + jb;
#pragma unroll
        for (int k = 0; k < 64; k++) {
            float hk = ybuf[k * 65 + n];
            CONV_K8(Wj + k * 64, hk);
        }
        const float* bj = b + jb;
        y[0] = fmaxf(fmaf(di, acc0.x, bj[0]), 0.f);
        y[1] = fmaxf(fmaf(di, acc0.y, bj[1]), 0.f);
        y[2] = fmaxf(fmaf(di, acc0.z, bj[2]), 0.f);
        y[3] = fmaxf(fmaf(di, acc0.w, bj[3]), 0.f);
        y[4] = fmaxf(fmaf(di, acc1.x, bj[4]), 0.f);
        y[5] = fmaxf(fmaf(di, acc1.y, bj[5]), 0.f);
        y[6] = fmaxf(fmaf(di, acc1.z, bj[6]), 0.f);
        y[7] = fmaxf(fmaf(di, acc1.w, bj[7]), 0.f);
    }
    __syncthreads();   // all conv reads of ybuf done
    if (i < N) {
#pragma unroll
        for (int jj = 0; jj < 8; jj++) ybuf[(jb + jj) * 65 + n] = y[jj];
    }
    __syncthreads();
    // heads: hd = tid>>8 (head), q2 = (tid>>6)&3 (8-out group), n = tid&63
    int hd = __builtin_amdgcn_readfirstlane(tid >> 8);        // 0/1, wave-uniform
    int q2 = __builtin_amdgcn_readfirstlane((tid >> 6) & 3);  // 0..3, wave-uniform
    int hb = q2 * 8;
    float op = 0.f;
    if (i < N) {
        const float* W1 = (hd ? W_i1 : W_d1) + hb;   // [64][32] row-major
        const float* b1 = (hd ? b_i1 : b_d1) + hb;
        const float* W2 = (hd ? W_i2 : W_d2) + hb;
        float4 acc0 = {0.f, 0.f, 0.f, 0.f}, acc1 = acc0;
#pragma unroll
        for (int k = 0; k < 64; k++) {
            float hk = ybuf[k * 65 + n];
            CONV_K8(W1 + k * 32, hk);
        }
        op = fmaf(fmaxf(acc0.x + b1[0], 0.f), W2[0], op);
        op = fmaf(fmaxf(acc0.y + b1[1], 0.f), W2[1], op);
        op = fmaf(fmaxf(acc0.z + b1[2], 0.f), W2[2], op);
        op = fmaf(fmaxf(acc0.w + b1[3], 0.f), W2[3], op);
        op = fmaf(fmaxf(acc1.x + b1[4], 0.f), W2[4], op);
        op = fmaf(fmaxf(acc1.y + b1[5], 0.f), W2[5], op);
        op = fmaf(fmaxf(acc1.z + b1[6], 0.f), W2[6], op);
        op = fmaf(fmaxf(acc1.w + b1[7], 0.f), W2[7], op);
    }
    opart[tid] = op;
    __syncthreads();
    if (tid < 128) {
        int n2 = tid & 63, h2 = tid >> 6;
        int i2 = base + n2;
        if (i2 < N) {
            int o0 = h2 * 256 + n2;
            float o = opart[o0] + opart[o0 + 64] + opart[o0 + 128] + opart[o0 + 192]
                    + (h2 ? b_i2[0] : b_d2[0]);
            out[(size_t)h2 * N + i2] = o;
        }
    }
}

extern "C" void kernel_launch(void* const* d_in, const int* in_sizes, int n_in,
                              void* d_out, int out_size, void* d_ws, size_t ws_size,
                              hipStream_t stream) {
    const float* x      = (const float*)d_in[0];
    const int*   ei     = (const int*)d_in[1];
    const float* W_enc  = (const float*)d_in[2];
    const float* b_enc  = (const float*)d_in[3];
    const float* conv_W = (const float*)d_in[4];
    const float* conv_b = (const float*)d_in[5];
    const float* W_d1   = (const float*)d_in[6];
    const float* b_d1   = (const float*)d_in[7];
    const float* W_d2   = (const float*)d_in[8];
    const float* b_d2   = (const float*)d_in[9];
    const float* W_i1   = (const float*)d_in[10];
    const float* b_i1   = (const float*)d_in[11];
    const float* W_i2   = (const float*)d_in[12];
    const float* b_i2   = (const float*)d_in[13];

    const int N = in_sizes[0] / 5;
    const int E = in_sizes[1] / 2;
    const int NB = (N + NPB - 1) >> NPB_SHIFT;   // <= 256

    // Workspace: hnA/hnB have N+1 rows (row N = dummy zeros for padding).
    // ebuf aliases hnA (dead before encoder writes hnA).
    unsigned* hnA = (unsigned*)d_ws;                      // (N+1)*32 bf16x2
    unsigned* hnB = hnA + (size_t)(N + 1) * 32;           // (N+1)*32
    float* dinv = (float*)(hnB + (size_t)(N + 1) * 32);
    unsigned* row_ptr = (unsigned*)(dinv + N);            // [N]
    unsigned short* pc8 = (unsigned short*)(row_ptr + N); // [N] (N even -> 4B-aligned end)
    unsigned* histT = (unsigned*)(pc8 + N);               // [NB*PB]
    unsigned* btot  = histT + (size_t)NB * PB;            // [NB]
    int* csr_pad    = (int*)(btot + NB);                  // [NB*BCAP]
    unsigned* ebuf  = (unsigned*)d_ws;                    // [E] packed (dead before encoder)
    float* out = (float*)d_out;

    const int gBlocks = (N + 63) / 64;   // 64 nodes per fused block

    // CSR build: bucket sort, no global atomics; padded output regions
    hist_pass<<<PB, 256, 0, stream>>>(ei + E, histT, E, NB);
    scan_bucket<<<NB, PB, 0, stream>>>(histT, btot);
    bin_pass<<<PB, 256, 0, stream>>>(ei, histT, btot, ebuf, E, NB);
    csr_pass<<<NB, 256, 0, stream>>>(ebuf, btot, row_ptr, pc8, dinv, csr_pad, N, E, NB);

    // encoder -> hnA (bf16, dinv-prescaled); zeroes dummy row N of hnA+hnB
    encoder<<<((N + 1) * 32 + 255) / 256, 256, 0, stream>>>(x, W_enc, b_enc, dinv,
                                                            hnA, hnB, N);

    // fused gather+conv per layer (ping-pong hnA/hnB), layer 2 fused with heads
    gconv<<<gBlocks, 512, 0, stream>>>(row_ptr, pc8, csr_pad, hnA,
                                       conv_W + 0 * HDIM * HDIM, conv_b + 0 * HDIM,
                                       dinv, hnB, N);
    gconv<<<gBlocks, 512, 0, stream>>>(row_ptr, pc8, csr_pad, hnB,
                                       conv_W + 1 * HDIM * HDIM, conv_b + 1 * HDIM,
                                       dinv, hnA, N);
    gconv_heads<<<gBlocks, 512, 0, stream>>>(row_ptr, pc8, csr_pad, hnA,
                                             conv_W + 2 * HDIM * HDIM, conv_b + 2 * HDIM,
                                             dinv, W_d1, b_d1, W_d2, b_d2,
                                             W_i1, b_i1, W_i2, b_i2, out, N);
}